// Round 2
// baseline (284.971 us; speedup 1.0000x reference)
//
#include <hip/hip_runtime.h>

// Problem constants: B=2048, V=256, T=11, K=8, N=8, H=255
constexpr int B_ = 2048;
constexpr int V_ = 256;
constexpr int T_ = 11;
constexpr int K_ = 8;
constexpr int N_ = 8;
constexpr int H_ = 255;
constexpr int TK = T_ * K_;          // 88 (t*8+k flat index within a b)
constexpr int XB = V_ * TK;          // 22528 floats per batch element
constexpr int SLAB = 92;             // hsh per-k stride: 92%4==0; 28k%32 distinct -> b128 reads conflict-free

// ---------------- kernel 0: transpose + pre-ReLU scanner_w ----------------
// sw (N,V,K) -> srw (V,K,N);  srw[v][k][n] = relu(sw[n][v][k])
// Valid because x is one-hot with coefficient exactly 1.0: h = sw[n, id, k].
__global__ __launch_bounds__(256)
void prep_srw(const float* __restrict__ sw, float* __restrict__ srw) {
    const int i = blockIdx.x * 256 + threadIdx.x;   // over V*K*N = 16384
    if (i < V_ * K_ * N_) {
        const int n  = i & 7;
        const int vk = i >> 3;
        const int k  = vk & 7;
        const int v  = vk >> 3;
        srw[i] = fmaxf(sw[(n * V_ + v) * K_ + k], 0.0f);
    }
}

// ---------------- kernel 1: one-hot index extraction (BW-bound) ----------------
// One block per b: scan 88 KB contiguously, write ids[b*88 + t*8 + k] = v.
// No atomics: exactly one nonzero per (t,k), so each slot has one writer.
__global__ __launch_bounds__(256, 6)
void scan_ids(const float* __restrict__ x, int* __restrict__ ids) {
    const int b   = blockIdx.x;
    const int tid = threadIdx.x;
    const float4* xb = (const float4*)(x + (size_t)b * XB);
    int* __restrict__ idb = ids + b * TK;

    // 5632 float4 per b = 22 per thread; chunks of 8/8/6 loads in flight
    #pragma unroll
    for (int c = 0; c < 3; ++c) {
        const int nload = (c < 2) ? 8 : 6;
        float4 vbuf[8];
        #pragma unroll
        for (int i = 0; i < 8; ++i)
            if (i < nload) vbuf[i] = xb[(c * 8 + i) * 256 + tid];
        #pragma unroll
        for (int i = 0; i < 8; ++i) {
            if (i < nload) {
                const float4 q = vbuf[i];
                if ((q.x + q.y) + (q.z + q.w) != 0.0f) {   // values are exactly 0.0/1.0
                    const int F = ((c * 8 + i) * 256 + tid) * 4;
                    if (q.x != 0.0f) { const int f = F;     const int v = f / TK; idb[f - v * TK] = v; }
                    if (q.y != 0.0f) { const int f = F + 1; const int v = f / TK; idb[f - v * TK] = v; }
                    if (q.z != 0.0f) { const int f = F + 2; const int v = f / TK; idb[f - v * TK] = v; }
                    if (q.w != 0.0f) { const int f = F + 3; const int v = f / TK; idb[f - v * TK] = v; }
                }
            }
        }
    }
}

// ---------------- kernel 2: MLP (compute-bound) ----------------
// One block per b. Phase A: gather srw rows by id into LDS slab [k][t*8+n].
// Phase B: thread (k2=tid>>5, hb=tid&31) -> rows k2*255 + hb + 32*i (coalesced
// hw/ow reads); h cached in registers (broadcast b128 LDS reads); butterfly reduce.
__global__ __launch_bounds__(256, 3)
void mlp(const int* __restrict__ ids, const float* __restrict__ srw,
         const float* __restrict__ hw, const float* __restrict__ ow,
         const float* __restrict__ ob, float* __restrict__ out) {
    __shared__ float hsh[K_ * SLAB];   // 736 floats: [k][t*8+n], already ReLU'd
    __shared__ float wred[4][22];

    const int tid = threadIdx.x;
    const int b   = blockIdx.x;

    // ---- phase A: gather (88 active threads) ----
    if (tid < TK) {
        const int v = ids[b * TK + tid] & 255;   // mask: safety vs poisoned ws
        const int t = tid >> 3;
        const int k = tid & 7;
        const float4* p = (const float4*)(srw + (v * K_ + k) * N_);
        const float4 a0 = p[0];
        const float4 a1 = p[1];
        float4* d = (float4*)(hsh + k * SLAB + t * 8);
        d[0] = a0;
        d[1] = a1;
    }
    __syncthreads();

    // ---- phase B ----
    const int k2 = tid >> 5;   // slot 0..7
    const int hb = tid & 31;

    float hreg[T_][N_];
    #pragma unroll
    for (int t = 0; t < T_; ++t) {
        const float4* p = (const float4*)(hsh + k2 * SLAB + t * 8);
        const float4 a0 = p[0];
        const float4 a1 = p[1];
        hreg[t][0] = a0.x; hreg[t][1] = a0.y; hreg[t][2] = a0.z; hreg[t][3] = a0.w;
        hreg[t][4] = a1.x; hreg[t][5] = a1.y; hreg[t][6] = a1.z; hreg[t][7] = a1.w;
    }

    float acc0[T_], acc1[T_];
    #pragma unroll
    for (int t = 0; t < T_; ++t) { acc0[t] = 0.0f; acc1[t] = 0.0f; }

    #pragma unroll
    for (int i = 0; i < 8; ++i) {
        const int hh = hb + 32 * i;          // 0..255, skip 255
        if (hh < H_) {
            const int row = k2 * H_ + hh;
            const float4* hwp = (const float4*)(hw + row * 8);
            const float4 w0 = hwp[0];
            const float4 w1 = hwp[1];
            const float o0 = ow[row];
            const float o1 = ow[K_ * H_ + row];
            #pragma unroll
            for (int t = 0; t < T_; ++t) {
                float pre = w0.x * hreg[t][0];
                pre = fmaf(w0.y, hreg[t][1], pre);
                pre = fmaf(w0.z, hreg[t][2], pre);
                pre = fmaf(w0.w, hreg[t][3], pre);
                pre = fmaf(w1.x, hreg[t][4], pre);
                pre = fmaf(w1.y, hreg[t][5], pre);
                pre = fmaf(w1.z, hreg[t][6], pre);
                pre = fmaf(w1.w, hreg[t][7], pre);
                const float h2 = fmaxf(pre, 0.0f);
                acc0[t] = fmaf(h2, o0, acc0[t]);
                acc1[t] = fmaf(h2, o1, acc1[t]);
            }
        }
    }

    // ---- reduce: 64-lane butterfly, then cross-wave ----
    #pragma unroll
    for (int t = 0; t < T_; ++t) {
        #pragma unroll
        for (int off = 32; off >= 1; off >>= 1) {
            acc0[t] += __shfl_xor(acc0[t], off, 64);
            acc1[t] += __shfl_xor(acc1[t], off, 64);
        }
    }
    const int wave = tid >> 6;
    const int lane = tid & 63;
    if (lane == 0) {
        #pragma unroll
        for (int t = 0; t < T_; ++t) {
            wred[wave][t]      = acc0[t];
            wred[wave][11 + t] = acc1[t];
        }
    }
    __syncthreads();

    if (tid < 22) {
        const float s = wred[0][tid] + wred[1][tid] + wred[2][tid] + wred[3][tid];
        out[(size_t)b * 22 + tid] = s + ob[tid / 11];
    }
}

extern "C" void kernel_launch(void* const* d_in, const int* in_sizes, int n_in,
                              void* d_out, int out_size, void* d_ws, size_t ws_size,
                              hipStream_t stream) {
    const float* x  = (const float*)d_in[0];  // (B,V,T,K)
    const float* sw = (const float*)d_in[1];  // (N,V,K)
    const float* hw = (const float*)d_in[2];  // (K*H,N)
    const float* ow = (const float*)d_in[3];  // (2,K*H)
    const float* ob = (const float*)d_in[4];  // (2,)
    float* out = (float*)d_out;               // (B,2,T)

    // ws layout: ids (B*88 ints = 720896 B) | srw (V*K*N floats = 65536 B)
    int*   ids = (int*)d_ws;
    float* srw = (float*)((char*)d_ws + (size_t)B_ * TK * sizeof(int));

    prep_srw<<<(V_ * K_ * N_ + 255) / 256, 256, 0, stream>>>(sw, srw);
    scan_ids<<<B_, 256, 0, stream>>>(x, ids);
    mlp<<<B_, 256, 0, stream>>>(ids, srw, hw, ow, ob, out);
}

// Round 3
// 271.861 us; speedup vs baseline: 1.0482x; 1.0482x over previous
//
#include <hip/hip_runtime.h>

// Problem constants: B=2048, V=256, T=11, K=8, N=8, H=255
constexpr int B_ = 2048;
constexpr int V_ = 256;
constexpr int T_ = 11;
constexpr int K_ = 8;
constexpr int N_ = 8;
constexpr int H_ = 255;
constexpr int TK = T_ * K_;          // 88 (t*8+k flat index within a b)
constexpr int XB = V_ * TK;          // 22528 floats per batch element
constexpr int SLAB = 92;             // hsh per-k stride: 28k%32 distinct -> b128 reads conflict-free

// ---------------- kernel 0: transpose + pre-ReLU scanner_w ----------------
// sw (N,V,K) -> srw (V,K,N); srw[v][k][n] = relu(sw[n][v][k]).
// Valid because x is one-hot with coefficient exactly 1.0: h = relu(sw[n,id,k]).
__global__ __launch_bounds__(256)
void prep_srw(const float* __restrict__ sw, float* __restrict__ srw) {
    const int i = blockIdx.x * 256 + threadIdx.x;   // over V*K*N = 16384
    if (i < V_ * K_ * N_) {
        const int n  = i & 7;
        const int vk = i >> 3;
        const int k  = vk & 7;
        const int v  = vk >> 3;
        srw[i] = fmaxf(sw[(n * V_ + v) * K_ + k], 0.0f);
    }
}

// ---------------- fused kernel: scan -> gather -> MLP ----------------
// One block per b. Phase A: scan 88 KB slab (coalesced float4), one-hot index
// -> LDS ids (no atomics: exactly one writer per (t,k)). Phase B: gather srw
// rows into hsh. Phase C: MLP with register-cached h, butterfly reduce.
// Compute of resident blocks overlaps the scan of the next block-wave.
__global__ __launch_bounds__(256, 3)
void scanner_fused(const float* __restrict__ x,    // (B,V,T,K)
                   const float* __restrict__ srw,  // (V,K,N) pre-ReLU'd
                   const float* __restrict__ hw,   // (K*H, N)
                   const float* __restrict__ ow,   // (2, K*H)
                   const float* __restrict__ ob,   // (2,)
                   float* __restrict__ out)        // (B,2,T)
{
    __shared__ int   ids_sh[TK];       // 88
    __shared__ float hsh[K_ * SLAB];   // 736 floats: [k][t*8+n], ReLU'd
    __shared__ float wred[4][22];

    const int tid = threadIdx.x;
    const int b   = blockIdx.x;

    // ---- phase A: scan slab for one-hot indices ----
    const float4* xb = (const float4*)(x + (size_t)b * XB);
    #pragma unroll
    for (int c = 0; c < 3; ++c) {
        const int nload = (c < 2) ? 8 : 6;   // 22 float4/thread total
        float4 vbuf[8];
        #pragma unroll
        for (int i = 0; i < 8; ++i)
            if (i < nload) vbuf[i] = xb[(c * 8 + i) * 256 + tid];
        #pragma unroll
        for (int i = 0; i < 8; ++i) {
            if (i < nload) {
                const float4 q = vbuf[i];
                if ((q.x + q.y) + (q.z + q.w) != 0.0f) {   // values exactly 0.0/1.0
                    const int F = ((c * 8 + i) * 256 + tid) * 4;
                    if (q.x != 0.0f) { const int f = F;     const int v = f / TK; ids_sh[f - v * TK] = v; }
                    if (q.y != 0.0f) { const int f = F + 1; const int v = f / TK; ids_sh[f - v * TK] = v; }
                    if (q.z != 0.0f) { const int f = F + 2; const int v = f / TK; ids_sh[f - v * TK] = v; }
                    if (q.w != 0.0f) { const int f = F + 3; const int v = f / TK; ids_sh[f - v * TK] = v; }
                }
            }
        }
    }
    __syncthreads();

    // ---- phase B: gather srw rows into hsh (88 active threads) ----
    if (tid < TK) {
        const int v = ids_sh[tid];
        const int t = tid >> 3;
        const int k = tid & 7;
        const float4* p = (const float4*)(srw + (v * K_ + k) * N_);
        const float4 a0 = p[0];
        const float4 a1 = p[1];
        float4* d = (float4*)(hsh + k * SLAB + t * 8);
        d[0] = a0;
        d[1] = a1;
    }
    __syncthreads();

    // ---- phase C: hidden layer + output accumulation ----
    const int k2 = tid >> 5;   // slot 0..7
    const int hb = tid & 31;

    float hreg[T_][N_];        // broadcast b128 LDS reads (same addr per k2 group)
    #pragma unroll
    for (int t = 0; t < T_; ++t) {
        const float4* p = (const float4*)(hsh + k2 * SLAB + t * 8);
        const float4 a0 = p[0];
        const float4 a1 = p[1];
        hreg[t][0] = a0.x; hreg[t][1] = a0.y; hreg[t][2] = a0.z; hreg[t][3] = a0.w;
        hreg[t][4] = a1.x; hreg[t][5] = a1.y; hreg[t][6] = a1.z; hreg[t][7] = a1.w;
    }

    float acc0[T_], acc1[T_];
    #pragma unroll
    for (int t = 0; t < T_; ++t) { acc0[t] = 0.0f; acc1[t] = 0.0f; }

    #pragma unroll
    for (int i = 0; i < 8; ++i) {
        const int hh = hb + 32 * i;          // 0..255, skip 255
        if (hh < H_) {
            const int row = k2 * H_ + hh;    // coalesced across hb
            const float4* hwp = (const float4*)(hw + row * 8);
            const float4 w0 = hwp[0];
            const float4 w1 = hwp[1];
            const float o0 = ow[row];
            const float o1 = ow[K_ * H_ + row];
            #pragma unroll
            for (int t = 0; t < T_; ++t) {
                float pre = w0.x * hreg[t][0];
                pre = fmaf(w0.y, hreg[t][1], pre);
                pre = fmaf(w0.z, hreg[t][2], pre);
                pre = fmaf(w0.w, hreg[t][3], pre);
                pre = fmaf(w1.x, hreg[t][4], pre);
                pre = fmaf(w1.y, hreg[t][5], pre);
                pre = fmaf(w1.z, hreg[t][6], pre);
                pre = fmaf(w1.w, hreg[t][7], pre);
                const float h2 = fmaxf(pre, 0.0f);
                acc0[t] = fmaf(h2, o0, acc0[t]);
                acc1[t] = fmaf(h2, o1, acc1[t]);
            }
        }
    }

    // ---- reduce: 64-lane butterfly, then cross-wave ----
    #pragma unroll
    for (int t = 0; t < T_; ++t) {
        #pragma unroll
        for (int off = 32; off >= 1; off >>= 1) {
            acc0[t] += __shfl_xor(acc0[t], off, 64);
            acc1[t] += __shfl_xor(acc1[t], off, 64);
        }
    }
    const int wave = tid >> 6;
    const int lane = tid & 63;
    if (lane == 0) {
        #pragma unroll
        for (int t = 0; t < T_; ++t) {
            wred[wave][t]      = acc0[t];
            wred[wave][11 + t] = acc1[t];
        }
    }
    __syncthreads();

    if (tid < 22) {
        const float s = wred[0][tid] + wred[1][tid] + wred[2][tid] + wred[3][tid];
        out[(size_t)b * 22 + tid] = s + ob[tid / 11];
    }
}

extern "C" void kernel_launch(void* const* d_in, const int* in_sizes, int n_in,
                              void* d_out, int out_size, void* d_ws, size_t ws_size,
                              hipStream_t stream) {
    const float* x  = (const float*)d_in[0];  // (B,V,T,K)
    const float* sw = (const float*)d_in[1];  // (N,V,K)
    const float* hw = (const float*)d_in[2];  // (K*H,N)
    const float* ow = (const float*)d_in[3];  // (2,K*H)
    const float* ob = (const float*)d_in[4];  // (2,)
    float* out = (float*)d_out;               // (B,2,T)

    float* srw = (float*)d_ws;                // V*K*N floats = 64 KB

    prep_srw<<<(V_ * K_ * N_ + 255) / 256, 256, 0, stream>>>(sw, srw);
    scanner_fused<<<B_, 256, 0, stream>>>(x, srw, hw, ow, ob, out);
}